// Round 11
// baseline (415.323 us; speedup 1.0000x reference)
//
#include <hip/hip_runtime.h>
#include <hip/hip_bf16.h>
#include <stdint.h>

typedef unsigned short u16;
typedef __bf16 bf16x8 __attribute__((ext_vector_type(8)));
typedef float f32x4 __attribute__((ext_vector_type(4)));
typedef unsigned short u16x8 __attribute__((ext_vector_type(8)));

#define QEPS 1e-8f

__device__ __forceinline__ u16 f32_to_bf16_rne(float f) {
    uint32_t u = __float_as_uint(f);
    u += 0x7fffu + ((u >> 16) & 1u);
    return (u16)(u >> 16);
}

// ---------------- x: f32 -> bf16, [M][K] row-major ----------------
__global__ void cvt_x_bf16(const float* __restrict__ x, u16* __restrict__ xb, int n8) {
    int idx = blockIdx.x * blockDim.x + threadIdx.x;
    if (idx >= n8) return;
    const float4* p = (const float4*)(x + (size_t)idx * 8);
    float4 a = p[0], b = p[1];
    u16x8 r;
    r[0] = f32_to_bf16_rne(a.x); r[1] = f32_to_bf16_rne(a.y);
    r[2] = f32_to_bf16_rne(a.z); r[3] = f32_to_bf16_rne(a.w);
    r[4] = f32_to_bf16_rne(b.x); r[5] = f32_to_bf16_rne(b.y);
    r[6] = f32_to_bf16_rne(b.z); r[7] = f32_to_bf16_rne(b.w);
    *(u16x8*)(xb + (size_t)idx * 8) = r;
}

// ------- weight dequant: w_dq[n][k] = round(w/s)*s, bf16, [N][K] -------
__global__ void dequant_w_bf16(const float* __restrict__ w, const float* __restrict__ ss,
                               u16* __restrict__ wb, int N, int K) {
    int idx = blockIdx.x * blockDim.x + threadIdx.x;
    int pr = K >> 3;
    if (idx >= N * pr) return;
    int n = idx / pr;
    int k8 = (idx - n * pr) << 3;
    float s = ss[(size_t)(k8 >> 7) * N + n] + QEPS;
    const float4* p = (const float4*)(w + (size_t)n * K + k8);
    float4 a = p[0], b = p[1];
    float v[8] = {a.x, a.y, a.z, a.w, b.x, b.y, b.z, b.w};
    u16x8 r;
#pragma unroll
    for (int i = 0; i < 8; ++i) {
        float q = rintf(v[i] / s);
        r[i] = f32_to_bf16_rne(q * s);
    }
    *(u16x8*)(wb + (size_t)n * K + k8) = r;
}

// ======================= 256x256 pipelined bf16 GEMM =======================
// A: global_load_lds -> swizzled LDS (ring-4 x BK=32, lookahead-3), woven
// register prefetch one slab ahead. B: DIRECT global->VGPR (L2-served, no LDS
// round trip) prefetched one slab ahead. LDS-port load/slab drops 96+32 ->
// 64+16 KiB, below the MFMA-pipe floor. One vmcnt + one barrier per slab.
#define BM 256
#define BN 256
#define SLOTB 16384     // A-only ring slot: 256 rows x 64 B
#define LDSB 65536      // 4 slots

#define ASYNC16(g, l)                                                                      \
    __builtin_amdgcn_global_load_lds((const __attribute__((address_space(1))) void*)(g),   \
                                     (__attribute__((address_space(3))) void*)(l), 16, 0, 0)
#define VMCNT(n) asm volatile("s_waitcnt vmcnt(" #n ")" ::: "memory")
#define BAR()    __builtin_amdgcn_s_barrier()
#define MFMA(a, b, c) __builtin_amdgcn_mfma_f32_16x16x32_bf16((a), (b), (c), 0, 0, 0)

__global__ __launch_bounds__(512, 2) void gemm_bf16_bt_256(
        const u16* __restrict__ A,    // [M][K] bf16
        const u16* __restrict__ B,    // [N][K] bf16
        const float* __restrict__ bias,
        float* __restrict__ C,        // [M][N] f32
        int M, int N, int K) {
    extern __shared__ char lds[];
    const int tid  = threadIdx.x;
    const int wave = tid >> 6;
    const int lane = tid & 63;

    // XCD-aware bijective swizzle (grid 512, %8==0)
    const int nwg = gridDim.x;
    const int cpx = nwg >> 3;
    const int bid = blockIdx.x;
    const int swz = (bid & 7) * cpx + (bid >> 3);
    const int nbn = N / BN;
    const int bm  = swz / nbn;
    const int bn  = swz - bm * nbn;

    const int wr = wave >> 2;                // 0..1 -> 128-row band
    const int wc = wave & 3;                 // 0..3 -> 64-col band

    // A staging sources (k pre-swizzled: kb ^= ((row>>1)&3)<<4)
    const int srow  = tid >> 2;                                        // 0..127
    const int kbsrc = ((tid & 3) << 4) ^ (((tid >> 3) & 3) << 4);
    const char* gA0 = (const char*)A + ((size_t)(bm * BM + srow) * K) * 2 + kbsrc;
    const char* gA1 = (const char*)A + ((size_t)(bm * BM + 128 + srow) * K) * 2 + kbsrc;

    auto STAGE = [&](int t) {
        const size_t ko = (size_t)t << 6;               // t * 32k * 2B
        char* d = lds + ((t & 3) * SLOTB) + (wave << 10);
        ASYNC16(gA0 + ko, d);
        ASYNC16(gA1 + ko, d + 8192);
    };

    // A fragment reads from LDS (same XOR on read address)
    const int kx = ((lane >> 4) ^ ((lane >> 1) & 3)) << 4;
    const char* pa = lds + (size_t)(wr * 128 + (lane & 15)) * 64 + kx;

    // B fragments DIRECT from global: lane holds row (band + n*16 + lr), k = kg*8..+8
    const u16* pbG = B + (size_t)(bn * BN + wc * 64 + (lane & 15)) * K + ((lane >> 4) << 3);

    f32x4 acc[8][4] = {};
    bf16x8 aX[8], bX[4], aY[8], bY[4];

#define RD_A(DST, i) DST[i] = *(const bf16x8*)(pa + bon + (i) * 1024)
#define LD_B(DST, t)                                                          \
    DST[0] = *(const bf16x8*)(pbG + (size_t)(t) * 32);                        \
    DST[1] = *(const bf16x8*)(pbG + (size_t)16 * K + (size_t)(t) * 32);       \
    DST[2] = *(const bf16x8*)(pbG + (size_t)32 * K + (size_t)(t) * 32);       \
    DST[3] = *(const bf16x8*)(pbG + (size_t)48 * K + (size_t)(t) * 32);
#define MROW(CA, CB, m)                                                       \
    acc[m][0] = MFMA(CA[m], CB[0], acc[m][0]);                                \
    acc[m][1] = MFMA(CA[m], CB[1], acc[m][1]);                                \
    acc[m][2] = MFMA(CA[m], CB[2], acc[m][2]);                                \
    acc[m][3] = MFMA(CA[m], CB[3], acc[m][3]);

    // slab t: compute (CA,CB); load B(t+1)->NB from global; stage A(t+3);
    // weave LDS reads of A(t+1)->NA between MFMAs.
#define SLAB(CA, CB, NA, NB, t, DO_STAGE, DO_BL, DO_WV, VMSTMT)               \
    {                                                                         \
        const int bon = (((t) + 1) & 3) * SLOTB;                              \
        if (DO_BL) { LD_B(NB, (t) + 1) }                                      \
        if (DO_STAGE) STAGE((t) + 3);                                         \
        __builtin_amdgcn_s_setprio(1);                                        \
        MROW(CA, CB, 0)                                                       \
        if (DO_WV) { RD_A(NA, 0); RD_A(NA, 1); }                              \
        MROW(CA, CB, 1)                                                       \
        if (DO_WV) { RD_A(NA, 2); RD_A(NA, 3); }                              \
        MROW(CA, CB, 2)                                                       \
        if (DO_WV) { RD_A(NA, 4); RD_A(NA, 5); }                              \
        MROW(CA, CB, 3)                                                       \
        if (DO_WV) { RD_A(NA, 6); RD_A(NA, 7); }                              \
        MROW(CA, CB, 4)                                                       \
        MROW(CA, CB, 5)                                                       \
        MROW(CA, CB, 6)                                                       \
        MROW(CA, CB, 7)                                                       \
        __builtin_amdgcn_s_setprio(0);                                        \
        VMSTMT;                                                               \
        BAR();                                                                \
    }

    const int NT = K >> 5;                   // 128 slabs of 32 k

    // prologue: B(0) loads [4], stage A0,A1,A2 [6]; VMCNT(2) drains B(0),A0,A1
    // (keeps A2); barrier seals A0,A1 for all waves; read slab-0 A frags.
    LD_B(bX, 0)
    STAGE(0); STAGE(1); STAGE(2);
    VMCNT(2);
    BAR();
    {
        const int bon = 0;
#pragma unroll
        for (int m = 0; m < 8; ++m) RD_A(aX, m);
    }

    // steady: end-of-slab queue [A(t+2):2, B(t+1):4, A(t+3):2] -> VMCNT(2)
    // confirms A(t+2) (sealed by barrier) and drains B(t+1) (own-wave regs).
    for (int t = 0; t < NT - 4; t += 2) {
        SLAB(aX, bX, aY, bY, t,     true, true, true, VMCNT(2))
        SLAB(aY, bY, aX, bX, t + 1, true, true, true, VMCNT(2))
    }
    SLAB(aX, bX, aY, bY, NT - 4, true,  true,  true,  VMCNT(2))  // stages A(NT-1)
    SLAB(aY, bY, aX, bX, NT - 3, false, true,  true,  VMCNT(0))  // seals A(NT-1), drains B(NT-2)
    SLAB(aX, bX, aY, bY, NT - 2, false, true,  true,  VMCNT(0))  // drains B(NT-1)
    SLAB(aY, bY, aX, bX, NT - 1, false, false, false, (void)0)

    // ---- epilogue: C/D layout row=(lane>>4)*4+i, col=lane&15 ----
    const int r0 = bm * BM + wr * 128 + ((lane >> 4) << 2);
    const int c0 = bn * BN + wc * 64 + (lane & 15);
    float bv[4];
#pragma unroll
    for (int n = 0; n < 4; ++n) bv[n] = bias[c0 + n * 16];
#pragma unroll
    for (int m = 0; m < 8; ++m)
#pragma unroll
        for (int n = 0; n < 4; ++n)
#pragma unroll
            for (int i = 0; i < 4; ++i)
                C[(size_t)(r0 + m * 16 + i) * N + (c0 + n * 16)] = acc[m][n][i] + bv[n];
}

extern "C" void kernel_launch(void* const* d_in, const int* in_sizes, int n_in,
                              void* d_out, int out_size, void* d_ws, size_t ws_size,
                              hipStream_t stream) {
    const float* x    = (const float*)d_in[0];   // [B,S,K] f32
    const float* w    = (const float*)d_in[1];   // [N,K]   f32
    const float* bias = (const float*)d_in[2];   // [N]     f32
    const float* ss   = (const float*)d_in[3];   // [K/128, N] f32
    float* out        = (float*)d_out;           // [B,S,N] f32

    const int N = in_sizes[2];            // 4096
    const int K = in_sizes[1] / N;        // 4096
    const int M = in_sizes[0] / K;        // 8192

    u16* xb = (u16*)d_ws;                        // [M][K] bf16
    u16* wb = xb + (size_t)M * K;                // [N][K] bf16

    int n8x = (M * K) >> 3;
    cvt_x_bf16<<<(n8x + 255) / 256, 256, 0, stream>>>(x, xb, n8x);

    int n8w = (N * K) >> 3;
    dequant_w_bf16<<<(n8w + 255) / 256, 256, 0, stream>>>(w, ss, wb, N, K);

    (void)hipFuncSetAttribute((const void*)gemm_bf16_bt_256,
                              hipFuncAttributeMaxDynamicSharedMemorySize, LDSB);
    dim3 grid((M / BM) * (N / BN));              // 32*16 = 512, %8 == 0
    gemm_bf16_bt_256<<<grid, 512, LDSB, stream>>>(xb, wb, bias, out, M, N, K);
}

// Round 12
// 317.266 us; speedup vs baseline: 1.3091x; 1.3091x over previous
//
#include <hip/hip_runtime.h>
#include <hip/hip_bf16.h>
#include <stdint.h>

typedef unsigned short u16;
typedef __bf16 bf16x8 __attribute__((ext_vector_type(8)));
typedef float f32x16 __attribute__((ext_vector_type(16)));
typedef unsigned short u16x8 __attribute__((ext_vector_type(8)));

#define QEPS 1e-8f

__device__ __forceinline__ u16 f32_to_bf16_rne(float f) {
    uint32_t u = __float_as_uint(f);
    u += 0x7fffu + ((u >> 16) & 1u);
    return (u16)(u >> 16);
}

// ---------------- x: f32 -> bf16, [M][K] row-major ----------------
__global__ void cvt_x_bf16(const float* __restrict__ x, u16* __restrict__ xb, int n8) {
    int idx = blockIdx.x * blockDim.x + threadIdx.x;
    if (idx >= n8) return;
    const float4* p = (const float4*)(x + (size_t)idx * 8);
    float4 a = p[0], b = p[1];
    u16x8 r;
    r[0] = f32_to_bf16_rne(a.x); r[1] = f32_to_bf16_rne(a.y);
    r[2] = f32_to_bf16_rne(a.z); r[3] = f32_to_bf16_rne(a.w);
    r[4] = f32_to_bf16_rne(b.x); r[5] = f32_to_bf16_rne(b.y);
    r[6] = f32_to_bf16_rne(b.z); r[7] = f32_to_bf16_rne(b.w);
    *(u16x8*)(xb + (size_t)idx * 8) = r;
}

// ------- weight dequant: w_dq[n][k] = round(w/s)*s, bf16, [N][K] -------
__global__ void dequant_w_bf16(const float* __restrict__ w, const float* __restrict__ ss,
                               u16* __restrict__ wb, int N, int K) {
    int idx = blockIdx.x * blockDim.x + threadIdx.x;
    int pr = K >> 3;
    if (idx >= N * pr) return;
    int n = idx / pr;
    int k8 = (idx - n * pr) << 3;
    float s = ss[(size_t)(k8 >> 7) * N + n] + QEPS;
    const float4* p = (const float4*)(w + (size_t)n * K + k8);
    float4 a = p[0], b = p[1];
    float v[8] = {a.x, a.y, a.z, a.w, b.x, b.y, b.z, b.w};
    u16x8 r;
#pragma unroll
    for (int i = 0; i < 8; ++i) {
        float q = rintf(v[i] / s);
        r[i] = f32_to_bf16_rne(q * s);
    }
    *(u16x8*)(wb + (size_t)n * K + k8) = r;
}

// ======================= 256x256 pipelined bf16 GEMM =======================
// R10 skeleton (ring-4 x BK=32, lookahead-3, end-of-slab vmcnt(4), 1 barrier,
// ping-pong register prefetch of slab t+1) with mfma_f32_32x32x16_bf16:
// same LDS traffic (12 b128/wave/slab), half the MFMA instructions, ~13%
// higher MFMA ceiling (2382 vs 2075 TF ubench).
#define BM 256
#define BN 256
#define SLOTB 32768     // bytes per ring slot: A 16K + B 16K
#define ABYT 16384
#define LDSB 131072

#define ASYNC16(g, l)                                                                      \
    __builtin_amdgcn_global_load_lds((const __attribute__((address_space(1))) void*)(g),   \
                                     (__attribute__((address_space(3))) void*)(l), 16, 0, 0)
#define VMCNT(n) asm volatile("s_waitcnt vmcnt(" #n ")" ::: "memory")
#define BAR()    __builtin_amdgcn_s_barrier()

__global__ __launch_bounds__(512, 2) void gemm_bf16_bt_256(
        const u16* __restrict__ A,    // [M][K] bf16
        const u16* __restrict__ B,    // [N][K] bf16
        const float* __restrict__ bias,
        float* __restrict__ C,        // [M][N] f32
        int M, int N, int K) {
    extern __shared__ char lds[];
    const int tid  = threadIdx.x;
    const int wave = tid >> 6;
    const int lane = tid & 63;

    // XCD-aware bijective swizzle (grid 512, %8==0)
    const int nwg = gridDim.x;
    const int cpx = nwg >> 3;
    const int bid = blockIdx.x;
    const int swz = (bid & 7) * cpx + (bid >> 3);
    const int nbn = N / BN;
    const int bm  = swz / nbn;
    const int bn  = swz - bm * nbn;

    const int wr = wave >> 2;                // 0..1 -> 128-row band
    const int wc = wave & 3;                 // 0..3 -> 64-col band

    // staging sources (k pre-swizzled: kb ^= ((row>>1)&3)<<4, involution in 64-B row)
    const int srow  = tid >> 2;                                        // 0..127
    const int kbsrc = ((tid & 3) << 4) ^ (((tid >> 3) & 3) << 4);
    const char* gA0 = (const char*)A + ((size_t)(bm * BM + srow) * K) * 2 + kbsrc;
    const char* gA1 = (const char*)A + ((size_t)(bm * BM + 128 + srow) * K) * 2 + kbsrc;
    const char* gB0 = (const char*)B + ((size_t)(bn * BN + srow) * K) * 2 + kbsrc;
    const char* gB1 = (const char*)B + ((size_t)(bn * BN + 128 + srow) * K) * 2 + kbsrc;

    auto STAGE = [&](int t) {
        const size_t ko = (size_t)t << 6;               // t * 32k * 2B
        char* d = lds + ((t & 3) * SLOTB) + (wave << 10);
        ASYNC16(gA0 + ko, d);
        ASYNC16(gA1 + ko, d + 8192);
        ASYNC16(gB0 + ko, d + ABYT);
        ASYNC16(gB1 + ko, d + ABYT + 8192);
    };

    // ---- 32x32x16 fragment reads ----
    // lane: row/col = lane&31, k-group hi = lane>>5; slot byte within 64-B row
    // = (kk<<5) ^ (hi<<4) ^ swz(row), swz = ((row>>1)&3)<<4 (row-band offsets
    // are multiples of 32 -> swz depends only on lane&31). Conflict-free under
    // 8-consecutive-lane issue groups (verified against bank model).
    const int lr = lane & 31;
    const int hi = lane >> 5;
    const int kx = (hi << 4) ^ (((lr >> 1) & 3) << 4);   // bits 4-5
    const char* pa = lds + (size_t)(wr * 128 + lr) * 64;
    const char* pb = lds + ABYT + (size_t)(wc * 64 + lr) * 64;

    f32x16 acc[4][2] = {};
    bf16x8 aX[8], bX[4], aY[8], bY[4];     // [m*2+kk], [n*2+kk]

#define RD_A(DST, m, kk) DST[(m)*2+(kk)] = *(const bf16x8*)(pa + bon + (m)*2048 + (kx ^ ((kk) << 5)))
#define RD_B(DST, n, kk) DST[(n)*2+(kk)] = *(const bf16x8*)(pb + bon + (n)*2048 + (kx ^ ((kk) << 5)))
#define MM(CA, CB, m, n, kk)                                                  \
    acc[m][n] = __builtin_amdgcn_mfma_f32_32x32x16_bf16(CA[(m)*2+(kk)], CB[(n)*2+(kk)], acc[m][n], 0, 0, 0);

    // slab t: 16 MFMA on (CA,CB); weave the 12 reads of slab t+1 into (NA,NB)
#define SLAB(CA, CB, NA, NB, t, DO_STAGE, DO_NEXT, VMSTMT)                    \
    {                                                                         \
        const int bon = (((t) + 1) & 3) * SLOTB;                              \
        if (DO_STAGE) STAGE((t) + 3);                                         \
        __builtin_amdgcn_s_setprio(1);                                        \
        MM(CA, CB, 0, 0, 0) if (DO_NEXT) { RD_B(NB, 0, 0); }                  \
        MM(CA, CB, 0, 1, 0) if (DO_NEXT) { RD_B(NB, 0, 1); }                  \
        MM(CA, CB, 1, 0, 0) if (DO_NEXT) { RD_B(NB, 1, 0); }                  \
        MM(CA, CB, 1, 1, 0) if (DO_NEXT) { RD_B(NB, 1, 1); }                  \
        MM(CA, CB, 2, 0, 0) if (DO_NEXT) { RD_A(NA, 0, 0); }                  \
        MM(CA, CB, 2, 1, 0) if (DO_NEXT) { RD_A(NA, 0, 1); }                  \
        MM(CA, CB, 3, 0, 0) if (DO_NEXT) { RD_A(NA, 1, 0); }                  \
        MM(CA, CB, 3, 1, 0) if (DO_NEXT) { RD_A(NA, 1, 1); }                  \
        MM(CA, CB, 0, 0, 1) if (DO_NEXT) { RD_A(NA, 2, 0); }                  \
        MM(CA, CB, 0, 1, 1) if (DO_NEXT) { RD_A(NA, 2, 1); }                  \
        MM(CA, CB, 1, 0, 1) if (DO_NEXT) { RD_A(NA, 3, 0); }                  \
        MM(CA, CB, 1, 1, 1) if (DO_NEXT) { RD_A(NA, 3, 1); }                  \
        MM(CA, CB, 2, 0, 1)                                                   \
        MM(CA, CB, 2, 1, 1)                                                   \
        MM(CA, CB, 3, 0, 1)                                                   \
        MM(CA, CB, 3, 1, 1)                                                   \
        __builtin_amdgcn_s_setprio(0);                                        \
        VMSTMT;                                                               \
        BAR();                                                                \
    }

    const int NT = K >> 5;                   // 128 slabs of 32 k

    // prologue: stage 0,1,2; vmcnt(4) confirms tiles 0 AND 1; barrier seals.
    STAGE(0); STAGE(1); STAGE(2);
    VMCNT(4);
    BAR();
    {
        const int bon = 0;
#pragma unroll
        for (int n = 0; n < 2; ++n) { RD_B(bX, n, 0); RD_B(bX, n, 1); }
#pragma unroll
        for (int m = 0; m < 4; ++m) { RD_A(aX, m, 0); RD_A(aX, m, 1); }
    }

    // steady: end-of-slab vmcnt(4) leaves only tile t+3 outstanding ->
    // confirms t+1 (next compute) and t+2 (next slab's woven prefetch).
    for (int t = 0; t < NT - 4; t += 2) {
        SLAB(aX, bX, aY, bY, t,     true, true, VMCNT(4))
        SLAB(aY, bY, aX, bX, t + 1, true, true, VMCNT(4))
    }
    SLAB(aX, bX, aY, bY, NT - 4, true,  true,  VMCNT(4))   // stages NT-1; confirms NT-3,NT-2
    SLAB(aY, bY, aX, bX, NT - 3, false, true,  VMCNT(0))   // confirms NT-1
    SLAB(aX, bX, aY, bY, NT - 2, false, true,  (void)0)
    SLAB(aY, bY, aX, bX, NT - 1, false, false, (void)0)

    // ---- epilogue: 32x32 C/D layout col=lane&31, row=(reg&3)+8*(reg>>2)+4*hi ----
    const int r0 = bm * BM + wr * 128 + 4 * hi;
    const int c0 = bn * BN + wc * 64 + lr;
    float bv0 = bias[c0], bv1 = bias[c0 + 32];
#pragma unroll
    for (int m = 0; m < 4; ++m)
#pragma unroll
        for (int g = 0; g < 4; ++g)
#pragma unroll
            for (int i = 0; i < 4; ++i) {
                const int row = r0 + m * 32 + 8 * g + i;
                C[(size_t)row * N + c0]      = acc[m][0][g * 4 + i] + bv0;
                C[(size_t)row * N + c0 + 32] = acc[m][1][g * 4 + i] + bv1;
            }
}

extern "C" void kernel_launch(void* const* d_in, const int* in_sizes, int n_in,
                              void* d_out, int out_size, void* d_ws, size_t ws_size,
                              hipStream_t stream) {
    const float* x    = (const float*)d_in[0];   // [B,S,K] f32
    const float* w    = (const float*)d_in[1];   // [N,K]   f32
    const float* bias = (const float*)d_in[2];   // [N]     f32
    const float* ss   = (const float*)d_in[3];   // [K/128, N] f32
    float* out        = (float*)d_out;           // [B,S,N] f32

    const int N = in_sizes[2];            // 4096
    const int K = in_sizes[1] / N;        // 4096
    const int M = in_sizes[0] / K;        // 8192

    u16* xb = (u16*)d_ws;                        // [M][K] bf16
    u16* wb = xb + (size_t)M * K;                // [N][K] bf16

    int n8x = (M * K) >> 3;
    cvt_x_bf16<<<(n8x + 255) / 256, 256, 0, stream>>>(x, xb, n8x);

    int n8w = (N * K) >> 3;
    dequant_w_bf16<<<(n8w + 255) / 256, 256, 0, stream>>>(w, ss, wb, N, K);

    (void)hipFuncSetAttribute((const void*)gemm_bf16_bt_256,
                              hipFuncAttributeMaxDynamicSharedMemorySize, LDSB);
    dim3 grid((M / BM) * (N / BN));              // 32*16 = 512, %8 == 0
    gemm_bf16_bt_256<<<grid, 512, LDSB, stream>>>(xb, wb, bias, out, M, N, K);
}

// Round 13
// 266.473 us; speedup vs baseline: 1.5586x; 1.1906x over previous
//
#include <hip/hip_runtime.h>
#include <hip/hip_bf16.h>
#include <stdint.h>

typedef unsigned short u16;
typedef __bf16 bf16x8 __attribute__((ext_vector_type(8)));
typedef float f32x4 __attribute__((ext_vector_type(4)));
typedef unsigned short u16x8 __attribute__((ext_vector_type(8)));

#define QEPS 1e-8f

__device__ __forceinline__ u16 f32_to_bf16_rne(float f) {
    uint32_t u = __float_as_uint(f);
    u += 0x7fffu + ((u >> 16) & 1u);
    return (u16)(u >> 16);
}

// ---------------- x: f32 -> bf16, [M][K] row-major ----------------
__global__ void cvt_x_bf16(const float* __restrict__ x, u16* __restrict__ xb, int n8) {
    int idx = blockIdx.x * blockDim.x + threadIdx.x;
    if (idx >= n8) return;
    const float4* p = (const float4*)(x + (size_t)idx * 8);
    float4 a = p[0], b = p[1];
    u16x8 r;
    r[0] = f32_to_bf16_rne(a.x); r[1] = f32_to_bf16_rne(a.y);
    r[2] = f32_to_bf16_rne(a.z); r[3] = f32_to_bf16_rne(a.w);
    r[4] = f32_to_bf16_rne(b.x); r[5] = f32_to_bf16_rne(b.y);
    r[6] = f32_to_bf16_rne(b.z); r[7] = f32_to_bf16_rne(b.w);
    *(u16x8*)(xb + (size_t)idx * 8) = r;
}

// ------- weight dequant: w_dq[n][k] = round(w/s)*s, bf16, [N][K] -------
__global__ void dequant_w_bf16(const float* __restrict__ w, const float* __restrict__ ss,
                               u16* __restrict__ wb, int N, int K) {
    int idx = blockIdx.x * blockDim.x + threadIdx.x;
    int pr = K >> 3;
    if (idx >= N * pr) return;
    int n = idx / pr;
    int k8 = (idx - n * pr) << 3;
    float s = ss[(size_t)(k8 >> 7) * N + n] + QEPS;
    const float4* p = (const float4*)(w + (size_t)n * K + k8);
    float4 a = p[0], b = p[1];
    float v[8] = {a.x, a.y, a.z, a.w, b.x, b.y, b.z, b.w};
    u16x8 r;
#pragma unroll
    for (int i = 0; i < 8; ++i) {
        float q = rintf(v[i] / s);
        r[i] = f32_to_bf16_rne(q * s);
    }
    *(u16x8*)(wb + (size_t)n * K + k8) = r;
}

// ======================= 256x256 pipelined bf16 GEMM =======================
// R10 skeleton (ring-4 x BK=32, lookahead-3, end-of-slab vmcnt(4) confirming
// t+1 AND t+2, one barrier/slab, ping-pong register prefetch of slab t+1)
// + m196's lever: the 4 global_load_lds of STAGE(t+3) are spread one-per-
// MFMA-row-cluster, fine-interleaved with the woven ds_reads.
#define BM 256
#define BN 256
#define SLOTB 32768     // bytes per ring slot: A 16K + B 16K
#define ABYT 16384
#define LDSB 131072

#define ASYNC16(g, l)                                                                      \
    __builtin_amdgcn_global_load_lds((const __attribute__((address_space(1))) void*)(g),   \
                                     (__attribute__((address_space(3))) void*)(l), 16, 0, 0)
#define VMCNT(n) asm volatile("s_waitcnt vmcnt(" #n ")" ::: "memory")
#define BAR()    __builtin_amdgcn_s_barrier()
#define MFMA(a, b, c) __builtin_amdgcn_mfma_f32_16x16x32_bf16((a), (b), (c), 0, 0, 0)

__global__ __launch_bounds__(512, 2) void gemm_bf16_bt_256(
        const u16* __restrict__ A,    // [M][K] bf16
        const u16* __restrict__ B,    // [N][K] bf16
        const float* __restrict__ bias,
        float* __restrict__ C,        // [M][N] f32
        int M, int N, int K) {
    extern __shared__ char lds[];
    const int tid  = threadIdx.x;
    const int wave = tid >> 6;
    const int lane = tid & 63;

    // XCD-aware bijective swizzle (grid 512, %8==0)
    const int nwg = gridDim.x;
    const int cpx = nwg >> 3;
    const int bid = blockIdx.x;
    const int swz = (bid & 7) * cpx + (bid >> 3);
    const int nbn = N / BN;
    const int bm  = swz / nbn;
    const int bn  = swz - bm * nbn;

    const int wr = wave >> 2;                // 0..1 -> 128-row band
    const int wc = wave & 3;                 // 0..3 -> 64-col band

    // staging sources (k pre-swizzled: kb ^= ((row>>1)&3)<<4, involution in 64-B row)
    const int srow  = tid >> 2;                                        // 0..127
    const int kbsrc = ((tid & 3) << 4) ^ (((tid >> 3) & 3) << 4);
    const char* gA0 = (const char*)A + ((size_t)(bm * BM + srow) * K) * 2 + kbsrc;
    const char* gA1 = (const char*)A + ((size_t)(bm * BM + 128 + srow) * K) * 2 + kbsrc;
    const char* gB0 = (const char*)B + ((size_t)(bn * BN + srow) * K) * 2 + kbsrc;
    const char* gB1 = (const char*)B + ((size_t)(bn * BN + 128 + srow) * K) * 2 + kbsrc;

    // one quarter of a slab's staging, selected by compile-time PART
    auto STG = [&](int t, int part) {
        const size_t ko = (size_t)t << 6;               // t * 32k * 2B
        char* d = lds + ((t & 3) * SLOTB) + (wave << 10);
        if (part == 0)      ASYNC16(gA0 + ko, d);
        else if (part == 1) ASYNC16(gA1 + ko, d + 8192);
        else if (part == 2) ASYNC16(gB0 + ko, d + ABYT);
        else                ASYNC16(gB1 + ko, d + ABYT + 8192);
    };

    // fragment read bases (same XOR on read address)
    const int kx = ((lane >> 4) ^ ((lane >> 1) & 3)) << 4;
    const char* pa = lds + (size_t)(wr * 128 + (lane & 15)) * 64 + kx;
    const char* pb = lds + ABYT + (size_t)(wc * 64 + (lane & 15)) * 64 + kx;

    f32x4 acc[8][4] = {};
    bf16x8 aX[8], bX[4], aY[8], bY[4];

#define RD_B(DST, i) DST[i] = *(const bf16x8*)(pb + bon + (i) * 1024)
#define RD_A(DST, i) DST[i] = *(const bf16x8*)(pa + bon + (i) * 1024)
#define MROW(CA, CB, m)                                                       \
    acc[m][0] = MFMA(CA[m], CB[0], acc[m][0]);                                \
    acc[m][1] = MFMA(CA[m], CB[1], acc[m][1]);                                \
    acc[m][2] = MFMA(CA[m], CB[2], acc[m][2]);                                \
    acc[m][3] = MFMA(CA[m], CB[3], acc[m][3]);

    // slab t: compute (CA,CB); weave next-slab reads into (NA,NB) AND spread
    // the 4 stage loads of slab t+3 one-per-row-cluster (m196 interleave).
#define SLAB(CA, CB, NA, NB, t, DO_STAGE, DO_NEXT, VMSTMT)                    \
    {                                                                         \
        const int bon = (((t) + 1) & 3) * SLOTB;                              \
        __builtin_amdgcn_s_setprio(1);                                        \
        MROW(CA, CB, 0)                                                       \
        if (DO_NEXT) { RD_B(NB, 0); RD_B(NB, 1); }                            \
        if (DO_STAGE) STG((t) + 3, 0);                                        \
        MROW(CA, CB, 1)                                                       \
        if (DO_NEXT) { RD_B(NB, 2); RD_B(NB, 3); }                            \
        if (DO_STAGE) STG((t) + 3, 1);                                        \
        MROW(CA, CB, 2)                                                       \
        if (DO_NEXT) { RD_A(NA, 0); RD_A(NA, 1); }                            \
        if (DO_STAGE) STG((t) + 3, 2);                                        \
        MROW(CA, CB, 3)                                                       \
        if (DO_NEXT) { RD_A(NA, 2); RD_A(NA, 3); }                            \
        if (DO_STAGE) STG((t) + 3, 3);                                        \
        MROW(CA, CB, 4)                                                       \
        if (DO_NEXT) { RD_A(NA, 4); RD_A(NA, 5); }                            \
        MROW(CA, CB, 5)                                                       \
        if (DO_NEXT) { RD_A(NA, 6); RD_A(NA, 7); }                            \
        MROW(CA, CB, 6)                                                       \
        MROW(CA, CB, 7)                                                       \
        __builtin_amdgcn_s_setprio(0);                                        \
        VMSTMT;                                                               \
        BAR();                                                                \
    }

    const int NT = K >> 5;                   // 128 slabs of 32 k

    // prologue: stage 0,1,2; vmcnt(4) confirms tiles 0 AND 1 (sealed by the
    // barrier for all waves); then load slab-0 fragments into set X.
    STG(0, 0); STG(0, 1); STG(0, 2); STG(0, 3);
    STG(1, 0); STG(1, 1); STG(1, 2); STG(1, 3);
    STG(2, 0); STG(2, 1); STG(2, 2); STG(2, 3);
    VMCNT(4);
    BAR();
    {
        const int bon = 0;
#pragma unroll
        for (int n = 0; n < 4; ++n) RD_B(bX, n);
#pragma unroll
        for (int m = 0; m < 8; ++m) RD_A(aX, m);
    }

    // steady: end-of-slab vmcnt(4) leaves only tile t+3 outstanding ->
    // confirms t+1 (next compute) and t+2 (next slab's woven prefetch).
    for (int t = 0; t < NT - 4; t += 2) {
        SLAB(aX, bX, aY, bY, t,     true, true, VMCNT(4))
        SLAB(aY, bY, aX, bX, t + 1, true, true, VMCNT(4))
    }
    SLAB(aX, bX, aY, bY, NT - 4, true,  true,  VMCNT(4))   // stages NT-1; confirms NT-3,NT-2
    SLAB(aY, bY, aX, bX, NT - 3, false, true,  VMCNT(0))   // confirms NT-1
    SLAB(aX, bX, aY, bY, NT - 2, false, true,  (void)0)
    SLAB(aY, bY, aX, bX, NT - 1, false, false, (void)0)

    // ---- epilogue: C/D layout row=(lane>>4)*4+i, col=lane&15 ----
    const int r0 = bm * BM + wr * 128 + ((lane >> 4) << 2);
    const int c0 = bn * BN + wc * 64 + (lane & 15);
    float bv[4];
#pragma unroll
    for (int n = 0; n < 4; ++n) bv[n] = bias[c0 + n * 16];
#pragma unroll
    for (int m = 0; m < 8; ++m)
#pragma unroll
        for (int n = 0; n < 4; ++n)
#pragma unroll
            for (int i = 0; i < 4; ++i)
                C[(size_t)(r0 + m * 16 + i) * N + (c0 + n * 16)] = acc[m][n][i] + bv[n];
}

extern "C" void kernel_launch(void* const* d_in, const int* in_sizes, int n_in,
                              void* d_out, int out_size, void* d_ws, size_t ws_size,
                              hipStream_t stream) {
    const float* x    = (const float*)d_in[0];   // [B,S,K] f32
    const float* w    = (const float*)d_in[1];   // [N,K]   f32
    const float* bias = (const float*)d_in[2];   // [N]     f32
    const float* ss   = (const float*)d_in[3];   // [K/128, N] f32
    float* out        = (float*)d_out;           // [B,S,N] f32

    const int N = in_sizes[2];            // 4096
    const int K = in_sizes[1] / N;        // 4096
    const int M = in_sizes[0] / K;        // 8192

    u16* xb = (u16*)d_ws;                        // [M][K] bf16
    u16* wb = xb + (size_t)M * K;                // [N][K] bf16

    int n8x = (M * K) >> 3;
    cvt_x_bf16<<<(n8x + 255) / 256, 256, 0, stream>>>(x, xb, n8x);

    int n8w = (N * K) >> 3;
    dequant_w_bf16<<<(n8w + 255) / 256, 256, 0, stream>>>(w, ss, wb, N, K);

    (void)hipFuncSetAttribute((const void*)gemm_bf16_bt_256,
                              hipFuncAttributeMaxDynamicSharedMemorySize, LDSB);
    dim3 grid((M / BM) * (N / BN));              // 32*16 = 512, %8 == 0
    gemm_bf16_bt_256<<<grid, 512, LDSB, stream>>>(xb, wb, bias, out, M, N, K);
}